// Round 5
// baseline (196.057 us; speedup 1.0000x reference)
//
#include <hip/hip_runtime.h>

// SuperLoss mean — closed-form via a quartic fit of Q(p) = exp(W0(y)).
//
// Reference: y = 0.5*max(-2/e, (l-tau)/lam) = max(-1/e, 2(l-tau)),
//            w = W0(y), sigma = exp(-w), loss = (l-tau)*sigma + lam*log(sigma)^2.
// Identities at the converged W (lam = 0.25):
//   unclamped: (l-tau)*sigma = 2*lam*w  =>  loss = 0.25*w*(w+2)
//   clamped (y = -1/e, w = -1):             loss = e*(l-tau) + 0.25   (EXACT, ~70% of data)
// Lambert W without iteration: p = sqrt(2*(1+e*y)), Q(p) = e^{W0(y)} quartic fit
// (|err| <= 2e-4 on p in [0, 5.092]); then w = y/Q.  Verified absmax ~0 in R4.
//
// R4 post-mortem: kernel was latency-stall-bound (2.6 TB/s, ~52 us) — only ~4
// loads in flight per wave. This version: 16 fully-unrolled loads per thread
// (affine addresses, hoistable), 4 independent accumulators, launch_bounds
// (256,4) to cap VGPR at 128 (4 waves/SIMD x 16 KB outstanding = 64 KB/SIMD).

#define TAU_F 5.799092654460526f
#define E_F   2.718281828459045f
#define NEG_INV_E_F (-0.36787944117144233f)

constexpr int PART_BLOCKS  = 2048;
constexpr int PART_THREADS = 256;
constexpr int PER_THREAD   = 16;   // float4 loads per thread: 2048*256*16 = 8M float4 = 2^25 floats

__device__ __forceinline__ float superloss_elem(float l) {
    float y2 = fmaf(2.0f, l, -2.0f * TAU_F);   // unclamped y = 2*(l - tau)
    float y  = fmaxf(NEG_INV_E_F, y2);         // y >= -1/e

    float s = fmaf(2.0f * E_F, y, 2.0f);       // p^2 = 2 + 2e*y  (>= 0)
    float p = __builtin_amdgcn_sqrtf(s);

    // Q = e^{W0(y)} quartic, Estrin using s = p^2 (short dep chain):
    float A = fmaf(0.36931500f, p, 0.36787944f);
    float B = fmaf(-0.00254460f, p, fmaf(0.00012854f, s, 0.05819100f));
    float Q = fmaf(s, B, A);

    float w = y * __builtin_amdgcn_rcpf(Q);    // w = y / e^w = W0(y)

    float loss_u = w * fmaf(0.25f, w, 0.5f);         // 0.25*w*(w+2)
    float loss_c = fmaf(0.5f * E_F, y2, 0.25f);      // e*(l-tau) + 0.25 (exact)
    return (y2 < NEG_INV_E_F) ? loss_c : loss_u;
}

__global__ __launch_bounds__(PART_THREADS, 4) void superloss_partial(
    const float4* __restrict__ in, float* __restrict__ partial, int n4) {
    const int tid    = blockIdx.x * PART_THREADS + threadIdx.x;
    const int stride = PART_BLOCKS * PART_THREADS;   // compile-time constant

    // Phase 1: issue all 16 independent loads (fully unrolled, affine addrs).
    float4 v[PER_THREAD];
#pragma unroll
    for (int k = 0; k < PER_THREAD; ++k) {
        int i = tid + k * stride;
        if (i < n4) v[k] = in[i];
        else        v[k] = make_float4(0.f, 0.f, 0.f, 0.f);  // dead for N=2^25
    }

    // Phase 2: compute with 4 independent accumulator chains.
    float a0 = 0.f, a1 = 0.f, a2 = 0.f, a3 = 0.f;
#pragma unroll
    for (int k = 0; k < PER_THREAD; ++k) {
        int i = tid + k * stride;
        if (i < n4) {
            a0 += superloss_elem(v[k].x);
            a1 += superloss_elem(v[k].y);
            a2 += superloss_elem(v[k].z);
            a3 += superloss_elem(v[k].w);
        }
    }
    // Generic fallback (dead for N=2^25, keeps kernel correct for any n4):
    for (int i = tid + PER_THREAD * stride; i < n4; i += stride) {
        float4 u = in[i];
        a0 += superloss_elem(u.x); a1 += superloss_elem(u.y);
        a2 += superloss_elem(u.z); a3 += superloss_elem(u.w);
    }
    float acc = (a0 + a1) + (a2 + a3);

    // Wave (64-lane) shuffle reduce.
#pragma unroll
    for (int off = 32; off > 0; off >>= 1) acc += __shfl_down(acc, off);

    __shared__ float s[PART_THREADS / 64];
    int lane = threadIdx.x & 63;
    int wave = threadIdx.x >> 6;
    if (lane == 0) s[wave] = acc;
    __syncthreads();
    if (threadIdx.x == 0) {
        float b = 0.0f;
#pragma unroll
        for (int i = 0; i < PART_THREADS / 64; ++i) b += s[i];
        partial[blockIdx.x] = b;
    }
}

__global__ __launch_bounds__(256) void superloss_final(
    const float* __restrict__ partial, int nblocks,
    const float* __restrict__ in, int tail_start, int n,
    float* __restrict__ out) {
    double acc = 0.0;
    for (int i = threadIdx.x; i < nblocks; i += 256) acc += (double)partial[i];
    if (threadIdx.x == 0) {  // scalar tail, no-op for N = 2^25
        for (int i = tail_start; i < n; ++i) acc += (double)superloss_elem(in[i]);
    }
#pragma unroll
    for (int off = 32; off > 0; off >>= 1) acc += __shfl_down(acc, off);

    __shared__ double s[4];
    int lane = threadIdx.x & 63;
    int wave = threadIdx.x >> 6;
    if (lane == 0) s[wave] = acc;
    __syncthreads();
    if (threadIdx.x == 0) {
        double t = s[0] + s[1] + s[2] + s[3];
        out[0] = (float)(t / (double)n);
    }
}

extern "C" void kernel_launch(void* const* d_in, const int* in_sizes, int n_in,
                              void* d_out, int out_size, void* d_ws, size_t ws_size,
                              hipStream_t stream) {
    const float* l_i = (const float*)d_in[0];
    float* out = (float*)d_out;
    float* partial = (float*)d_ws;   // PART_BLOCKS floats = 8 KB scratch

    int n  = in_sizes[0];
    int n4 = n >> 2;

    superloss_partial<<<PART_BLOCKS, PART_THREADS, 0, stream>>>(
        (const float4*)l_i, partial, n4);
    superloss_final<<<1, 256, 0, stream>>>(
        partial, PART_BLOCKS, l_i, n4 << 2, n, out);
}

// Round 6
// 182.379 us; speedup vs baseline: 1.0750x; 1.0750x over previous
//
#include <hip/hip_runtime.h>

// SuperLoss mean — closed-form via a quartic fit of Q(p) = exp(W0(y)).
//
// Math (verified absmax ~0 in R4):
//   y = max(-1/e, 2*(l-tau)); p = sqrt(2+2e*y); Q(p) ~= e^{W0(y)} (quartic,
//   |err|<=2e-4 on p in [0,5.092]); w = y/Q  [w*e^w = y].
//   unclamped loss = 0.25*w*(w+2);  clamped loss = e*(l-tau)+0.25 (exact).
//
// R5 post-mortem: per-load `if` guards -> 16 exec-mask toggles serialized the
// load batch (52 -> 69 us). R4 plain loop was exposed-latency-bound (2.6 TB/s).
// This version: ONE per-thread uniform branch to an exact fast path; inside,
// a 2-stage software pipeline (4 loads compute-pending + 4 prefetched = 8
// outstanding dwordx4/wave), no per-load masks, no launch_bounds VGPR cap.

#define TAU_F 5.799092654460526f
#define E_F   2.718281828459045f
#define NEG_INV_E_F (-0.36787944117144233f)

constexpr int PART_BLOCKS  = 2048;
constexpr int PART_THREADS = 256;
constexpr int PER_THREAD   = 16;   // 2048*256*16 float4 = 2^25 floats exactly

typedef float nat_float4 __attribute__((ext_vector_type(4)));

__device__ __forceinline__ float superloss_elem(float l) {
    float y2 = fmaf(2.0f, l, -2.0f * TAU_F);   // unclamped y = 2*(l - tau)
    float y  = fmaxf(NEG_INV_E_F, y2);         // y >= -1/e

    float s = fmaf(2.0f * E_F, y, 2.0f);       // p^2 = 2 + 2e*y  (>= 0)
    float p = __builtin_amdgcn_sqrtf(s);

    // Q = e^{W0(y)} quartic, Estrin on s = p^2 (short dep chain):
    float A = fmaf(0.36931500f, p, 0.36787944f);
    float B = fmaf(-0.00254460f, p, fmaf(0.00012854f, s, 0.05819100f));
    float Q = fmaf(s, B, A);

    float w = y * __builtin_amdgcn_rcpf(Q);    // w = y / e^w = W0(y)

    float loss_u = w * fmaf(0.25f, w, 0.5f);       // 0.25*w*(w+2)
    float loss_c = fmaf(0.5f * E_F, y2, 0.25f);    // e*(l-tau)+0.25 (exact)
    return (y2 < NEG_INV_E_F) ? loss_c : loss_u;
}

__global__ __launch_bounds__(PART_THREADS) void superloss_partial(
    const float* __restrict__ in_f, float* __restrict__ partial, int n4) {
    const nat_float4* __restrict__ in = (const nat_float4*)in_f;
    const int tid = blockIdx.x * PART_THREADS + threadIdx.x;
    const int S   = PART_BLOCKS * PART_THREADS;   // 524288 float4

    float a0 = 0.f, a1 = 0.f, a2 = 0.f, a3 = 0.f;

    if (tid + (PER_THREAD - 1) * S < n4) {
        // Exact fast path (all threads for N = 2^25): no per-load guards.
        nat_float4 cur[4], nxt[4];
#pragma unroll
        for (int j = 0; j < 4; ++j)
            cur[j] = __builtin_nontemporal_load(in + tid + j * S);

#pragma unroll
        for (int g = 0; g < 4; ++g) {
            if (g < 3) {            // prefetch next group while computing this one
#pragma unroll
                for (int j = 0; j < 4; ++j)
                    nxt[j] = __builtin_nontemporal_load(in + tid + (4 * g + 4 + j) * S);
            }
#pragma unroll
            for (int j = 0; j < 4; ++j) {
                a0 += superloss_elem(cur[j].x);
                a1 += superloss_elem(cur[j].y);
                a2 += superloss_elem(cur[j].z);
                a3 += superloss_elem(cur[j].w);
            }
#pragma unroll
            for (int j = 0; j < 4; ++j) cur[j] = nxt[j];   // register rename
        }
    } else {
        // Generic path (dead for N = 2^25; keeps any-n correctness).
        for (int i = tid; i < n4; i += S) {
            nat_float4 v = in[i];
            a0 += superloss_elem(v.x); a1 += superloss_elem(v.y);
            a2 += superloss_elem(v.z); a3 += superloss_elem(v.w);
        }
    }
    float acc = (a0 + a1) + (a2 + a3);

    // Wave (64-lane) shuffle reduce.
#pragma unroll
    for (int off = 32; off > 0; off >>= 1) acc += __shfl_down(acc, off);

    __shared__ float s[PART_THREADS / 64];
    int lane = threadIdx.x & 63;
    int wave = threadIdx.x >> 6;
    if (lane == 0) s[wave] = acc;
    __syncthreads();
    if (threadIdx.x == 0) {
        float b = 0.0f;
#pragma unroll
        for (int i = 0; i < PART_THREADS / 64; ++i) b += s[i];
        partial[blockIdx.x] = b;
    }
}

__global__ __launch_bounds__(256) void superloss_final(
    const float* __restrict__ partial, int nblocks,
    const float* __restrict__ in, int tail_start, int n,
    float* __restrict__ out) {
    double acc = 0.0;
    for (int i = threadIdx.x; i < nblocks; i += 256) acc += (double)partial[i];
    if (threadIdx.x == 0) {  // scalar tail, no-op for N = 2^25
        for (int i = tail_start; i < n; ++i) acc += (double)superloss_elem(in[i]);
    }
#pragma unroll
    for (int off = 32; off > 0; off >>= 1) acc += __shfl_down(acc, off);

    __shared__ double s[4];
    int lane = threadIdx.x & 63;
    int wave = threadIdx.x >> 6;
    if (lane == 0) s[wave] = acc;
    __syncthreads();
    if (threadIdx.x == 0) {
        double t = s[0] + s[1] + s[2] + s[3];
        out[0] = (float)(t / (double)n);
    }
}

extern "C" void kernel_launch(void* const* d_in, const int* in_sizes, int n_in,
                              void* d_out, int out_size, void* d_ws, size_t ws_size,
                              hipStream_t stream) {
    const float* l_i = (const float*)d_in[0];
    float* out = (float*)d_out;
    float* partial = (float*)d_ws;   // PART_BLOCKS floats = 8 KB scratch

    int n  = in_sizes[0];
    int n4 = n >> 2;

    superloss_partial<<<PART_BLOCKS, PART_THREADS, 0, stream>>>(
        l_i, partial, n4);
    superloss_final<<<1, 256, 0, stream>>>(
        partial, PART_BLOCKS, l_i, n4 << 2, n, out);
}